// Round 22
// baseline (109.650 us; speedup 1.0000x reference)
//
#include <hip/hip_runtime.h>
#include <math.h>

namespace {

constexpr int SOUT = 12;    // (14-3)/1+1
constexpr int OCAP = 32;
constexpr int PD   = 16;    // 4x4 pose
constexpr int NI   = 288;   // 3*3*32
constexpr int NPOS = 4 * SOUT * SOUT;  // 576 positions
constexpr float EPSF = 1e-9f;
constexpr size_t POSE_OUT = (size_t)NPOS * OCAP * PD;  // 294912

typedef float v2f __attribute__((ext_vector_type(2)));

__device__ __forceinline__ v2f vfma(v2f a, v2f b, v2f c) { return __builtin_elementwise_fma(a, b, c); }
__device__ __forceinline__ v2f splat(float a) { v2f r; r.x = a; r.y = a; return r; }

// DPP lane exchange (compile-time ctrl); folds into v_add_f32_dpp.
template<int CTRL>
__device__ __forceinline__ float dppf(float x) {
    return __int_as_float(__builtin_amdgcn_update_dpp(0, __float_as_int(x), CTRL, 0xF, 0xF, true));
}
// ds_swizzle xor-16 within 32-lane groups (BitMode: offset = (xor<<10) | and=0x1F)
#define SWZ16(x) __int_as_float(__builtin_amdgcn_ds_swizzle(__float_as_int(x), (16 << 10) | 0x1F))

// 32-lane all-reduce sum (4 DPP levels + 1 swizzle)
__device__ __forceinline__ float redsum32(float x) {
    x += dppf<0xB1>(x);
    x += dppf<0x4E>(x);
    x += dppf<0x141>(x);
    x += dppf<0x140>(x);
    x += SWZ16(x);
    return x;
}

// W row (16 floats) as 8 packed pairs over r
__device__ __forceinline__ void loadW(const float* __restrict__ p, v2f (&W)[8]) {
    const float4 w0 = *reinterpret_cast<const float4*>(p);
    const float4 w1 = *reinterpret_cast<const float4*>(p + 4);
    const float4 w2 = *reinterpret_cast<const float4*>(p + 8);
    const float4 w3 = *reinterpret_cast<const float4*>(p + 12);
    W[0].x=w0.x; W[0].y=w0.y; W[1].x=w0.z; W[1].y=w0.w;
    W[2].x=w1.x; W[2].y=w1.y; W[3].x=w1.z; W[3].y=w1.w;
    W[4].x=w2.x; W[4].y=w2.y; W[5].x=w2.z; W[5].y=w2.w;
    W[6].x=w3.x; W[6].y=w3.y; W[7].x=w3.z; W[7].y=w3.w;
}

// votes: v[p*2+h] holds pose dims (4p+2h, 4p+2h+1)... flattened as v[h2] = dims (2*h2, 2*h2+1)
__device__ __forceinline__ void vote8(const float* __restrict__ pr, const v2f (&W)[8], v2f (&v)[8]) {
    #pragma unroll
    for (int p = 0; p < 4; ++p) {
        const float4 pv = *reinterpret_cast<const float4*>(pr + p * 4);
        #pragma unroll
        for (int h = 0; h < 2; ++h) {
            v2f acc = splat(pv.w) * W[6 + h];
            acc = vfma(splat(pv.z), W[4 + h], acc);
            acc = vfma(splat(pv.y), W[2 + h], acc);
            acc = vfma(splat(pv.x), W[0 + h], acc);
            v[p * 2 + h] = acc;
        }
    }
}

// ---------------------------------------------------------------------------
// Single fused kernel, 512 threads = 8 waves per block, one block per n.
// slot = t>>5 (0..15): 16 i per block-step -> 18 steps cover 288 i per sweep.
// Per-wave serial chain HALVES vs the 256-thread version (54 vs 108 softmax
// chains across 3 sweeps) while resident waves/CU DOUBLE (2.25 blocks x 8) —
// both attack the measured latency-boundedness (R21: VALUBusy 36%, occ 14.5%).
// Stats block-local in LDS between sweeps (no workspace, staged once).
// launch_bounds (512,2): VGPR cap 2048/16 = 128 >= ~108 (R5: (512,2)->80 ok).
// ---------------------------------------------------------------------------
__global__ __launch_bounds__(512, 2)
void caps_fused(const float* __restrict__ pose_in,   // [4,14,14,32,16]
                const float* __restrict__ act_in,    // [4,14,14,32]
                const float* __restrict__ wmat,      // [288,32,16]
                const float* __restrict__ beta_v,    // [32]
                const float* __restrict__ beta_a,    // [32]
                float* __restrict__ out)             // pose ++ act
{
    __shared__ __align__(16) float sP[NI * PD];      // 18.4 KB full patch
    __shared__ float sA[NI];
    __shared__ __align__(8) float sStat[OCAP][2 * PD + 2]; // [o][0..15]=i2, [16..31]=ng
    __shared__ float sBias[OCAP];
    __shared__ float sRed[4][33][33];                // 2-phase cross-wave partials (17.4 KB)

    const int n  = blockIdx.x;
    const int b  = n / (SOUT * SOUT);
    const int yx = n % (SOUT * SOUT);
    const int y  = yx / SOUT;
    const int x  = yx % SOUT;

    const int t    = threadIdx.x;        // 0..511
    const int wave = t >> 6;             // 0..7
    const int o    = t & 31;
    const int slot = t >> 5;             // 0..15
    const int half = slot & 1;

    // ---- stage the full 288-cap patch ONCE (coalesced float4) ----
    {
        const float4* src = reinterpret_cast<const float4*>(pose_in);
        float4* dst = reinterpret_cast<float4*>(sP);
        for (int u = t; u < NI * 4; u += 512) {      // 1152 float4
            const int i = u >> 2, comp = u & 3;
            const int k = i >> 5, c = i & 31;
            const int ki = k / 3, kj = k - ki * 3;
            const int cell = (b * 14 + y + ki) * 14 + (x + kj);
            dst[u] = src[(size_t)(cell * 32 + c) * 4 + comp];
        }
        for (int u = t; u < NI; u += 512) {
            const int k = u >> 5, c = u & 31;
            const int ki = k / 3, kj = k - ki * 3;
            const int cell = (b * 14 + y + ki) * 14 + (x + kj);
            sA[u] = act_in[(size_t)cell * 32 + c];
        }
    }
    __syncthreads();

    // lane W base: i = step*16 + slot, row (i*32+o)*16; step stride 8192 floats
    const float* wth = wmat + ((size_t)(slot * OCAP + o)) * PD;

    #pragma unroll 1
    for (int sweep = 0; sweep < 3; ++sweep) {
        // per-sweep register cache of the per-o stats
        float bias_r = 0.f;
        v2f i2r[8], ngr[8];
        if (sweep > 0) {
            bias_r = sBias[o];
            #pragma unroll
            for (int h = 0; h < 8; ++h) {
                i2r[h] = *reinterpret_cast<const v2f*>(&sStat[o][2 * h]);
                ngr[h] = *reinterpret_cast<const v2f*>(&sStat[o][16 + 2 * h]);
            }
        }

        v2f s1[8], s2[8];
        float s0acc = 0.f;
        #pragma unroll
        for (int h = 0; h < 8; ++h) { s1[h] = splat(0.f); s2[h] = splat(0.f); }

        v2f WA[8], WB[8];
        loadW(wth, WA);

#define STEP(st_, Wc, Wn)                                                  \
        {                                                                  \
            if ((st_) < 17) loadW(wth + (size_t)((st_) + 1) * 8192, Wn);   \
            const int il = (st_) * 16 + slot;                              \
            v2f v[8];                                                      \
            vote8(&sP[il * PD], Wc, v);                                    \
            const float a_i = sA[il];                                      \
            float rrp;                                                     \
            if (sweep == 0) {                                              \
                rrp = a_i * (1.0f / 32.0f);                                \
            } else {                                                       \
                v2f ts2 = splat(0.f);                                      \
                _Pragma("unroll")                                          \
                for (int h = 0; h < 8; ++h) {                              \
                    const v2f tmp = vfma(v[h], i2r[h], ngr[h]);            \
                    ts2 = vfma(v[h], tmp, ts2);                            \
                }                                                          \
                /* shift-invariant softmax, no max-sub (validated R13) */  \
                const float zz = bias_r - (ts2.x + ts2.y);                 \
                const float e = __expf(zz);                                \
                const float es = redsum32(e);                              \
                rrp = __fdividef(e, es) * a_i;                             \
            }                                                              \
            s0acc += rrp;                                                  \
            const v2f rr2 = splat(rrp);                                    \
            _Pragma("unroll")                                              \
            for (int h = 0; h < 8; ++h) {                                  \
                const v2f rv = rr2 * v[h];                                 \
                s1[h] = s1[h] + rv;                                        \
                s2[h] = vfma(rv, v[h], s2[h]);                             \
            }                                                              \
        }

        #pragma unroll 1
        for (int kk = 0; kk < 9; ++kk) {
            STEP(2 * kk,     WA, WB);
            STEP(2 * kk + 1, WB, WA);
        }
#undef STEP

        // fold slot pairs (lane^32: different i, same o) within each wave
        #pragma unroll
        for (int h = 0; h < 8; ++h) {
            s1[h].x += __shfl_xor(s1[h].x, 32, 64);
            s1[h].y += __shfl_xor(s1[h].y, 32, 64);
            s2[h].x += __shfl_xor(s2[h].x, 32, 64);
            s2[h].y += __shfl_xor(s2[h].y, 32, 64);
        }
        s0acc += __shfl_xor(s0acc, 32, 64);

        // two-phase cross-wave reduction into sRed[4] (waves 0-3 store, 4-7 add)
        if (wave < 4 && half == 0) {
            #pragma unroll
            for (int h = 0; h < 8; ++h) {
                sRed[wave][2 * h][o]          = s1[h].x;
                sRed[wave][2 * h + 1][o]      = s1[h].y;
                sRed[wave][16 + 2 * h][o]     = s2[h].x;
                sRed[wave][16 + 2 * h + 1][o] = s2[h].y;
            }
            sRed[wave][32][o] = s0acc;
        }
        __syncthreads();
        if (wave >= 4 && half == 0) {
            #pragma unroll
            for (int h = 0; h < 8; ++h) {
                sRed[wave - 4][2 * h][o]          += s1[h].x;
                sRed[wave - 4][2 * h + 1][o]      += s1[h].y;
                sRed[wave - 4][16 + 2 * h][o]     += s2[h].x;
                sRed[wave - 4][16 + 2 * h + 1][o] += s2[h].y;
            }
            sRed[wave - 4][32][o] += s0acc;
        }
        __syncthreads();

        // ---- block-local stats (sweep<2) or final output (sweep==2) ----
        if (t < 256) {
            const int oo = t >> 3, dp = t & 7, d0 = dp * 2;
            float S0 = 0.f, S1a = 0.f, S1b = 0.f, S2a = 0.f, S2b = 0.f;
            #pragma unroll
            for (int r = 0; r < 4; ++r) {
                S0  += sRed[r][32][oo];
                S1a += sRed[r][d0][oo];
                S1b += sRed[r][d0 + 1][oo];
                S2a += sRed[r][16 + d0][oo];
                S2b += sRed[r][17 + d0][oo];
            }
            const float inv = 1.f / S0;
            const float m0 = S1a * inv, m1 = S1b * inv;
            const float v0 = fmaxf(fmaf(-m0, m0, S2a * inv), 0.f);
            const float v1 = fmaxf(fmaf(-m1, m1, S2b * inv), 0.f);
            float ll = __logf(sqrtf(v0) + EPSF) + __logf(sqrtf(v1) + EPSF);

            if (sweep < 2) {
                const float i20 = 0.5f / fmaxf(v0, 1e-30f);
                const float i21 = 0.5f / fmaxf(v1, 1e-30f);
                float c0 = m0 * m0 * i20 + m1 * m1 * i21;
                sStat[oo][d0]      = i20;
                sStat[oo][d0 + 1]  = i21;
                sStat[oo][16 + d0] = -2.f * m0 * i20;
                sStat[oo][17 + d0] = -2.f * m1 * i21;
                #pragma unroll
                for (int m = 1; m <= 4; m <<= 1) {
                    ll += __shfl_xor(ll, m, 8);
                    c0 += __shfl_xor(c0, m, 8);
                }
                if (dp == 0) {
                    const float cost = S0 * fmaf(16.f, beta_v[oo], ll);
                    const float invtemp = 1.0f + (float)sweep;   // 1, 2
                    const float oact = 1.f / (1.f + __expf(-invtemp * (beta_a[oo] - cost)));
                    sBias[oo] = __logf(oact + EPSF) - ll - c0;
                }
            } else {
                float2 pv; pv.x = m0; pv.y = m1;
                *reinterpret_cast<float2*>(out + (size_t)n * (OCAP * PD) + oo * PD + d0) = pv;
                #pragma unroll
                for (int m = 1; m <= 4; m <<= 1)
                    ll += __shfl_xor(ll, m, 8);
                if (dp == 0) {
                    const float cost = S0 * fmaf(16.f, beta_v[oo], ll);
                    const float oact = 1.f / (1.f + __expf(-3.0f * (beta_a[oo] - cost)));
                    out[POSE_OUT + (size_t)n * OCAP + oo] = oact;
                }
            }
        }
        __syncthreads();   // sStat/sBias visible; sRed safe to overwrite
    }
}

} // namespace

extern "C" void kernel_launch(void* const* d_in, const int* in_sizes, int n_in,
                              void* d_out, int out_size, void* d_ws, size_t ws_size,
                              hipStream_t stream) {
    const float* pose_in = (const float*)d_in[0];
    const float* act_in  = (const float*)d_in[1];
    const float* wmat    = (const float*)d_in[2];
    const float* beta_v  = (const float*)d_in[3];
    const float* beta_a  = (const float*)d_in[4];
    float* out = (float*)d_out;

    caps_fused<<<dim3(NPOS), dim3(512), 0, stream>>>(
        pose_in, act_in, wmat, beta_v, beta_a, out);
}

// Round 23
// 107.046 us; speedup vs baseline: 1.0243x; 1.0243x over previous
//
#include <hip/hip_runtime.h>
#include <math.h>

namespace {

constexpr int SOUT = 12;    // (14-3)/1+1
constexpr int OCAP = 32;
constexpr int PD   = 16;    // 4x4 pose
constexpr int NI   = 288;   // 3*3*32
constexpr int NPOS = 4 * SOUT * SOUT;  // 576 positions
constexpr float EPSF = 1e-9f;
constexpr size_t POSE_OUT = (size_t)NPOS * OCAP * PD;  // 294912

typedef float v2f __attribute__((ext_vector_type(2)));

__device__ __forceinline__ v2f vfma(v2f a, v2f b, v2f c) { return __builtin_elementwise_fma(a, b, c); }
__device__ __forceinline__ v2f splat(float a) { v2f r; r.x = a; r.y = a; return r; }

// DPP lane exchange (compile-time ctrl); folds into v_add_f32_dpp.
template<int CTRL>
__device__ __forceinline__ float dppf(float x) {
    return __int_as_float(__builtin_amdgcn_update_dpp(0, __float_as_int(x), CTRL, 0xF, 0xF, true));
}
// ds_swizzle xor-16 within 32-lane groups (BitMode: offset = (xor<<10) | and=0x1F)
#define SWZ16(x) __int_as_float(__builtin_amdgcn_ds_swizzle(__float_as_int(x), (16 << 10) | 0x1F))

// 32-lane all-reduce sum (4 DPP levels + 1 swizzle)
__device__ __forceinline__ float redsum32(float x) {
    x += dppf<0xB1>(x);
    x += dppf<0x4E>(x);
    x += dppf<0x141>(x);
    x += dppf<0x140>(x);
    x += SWZ16(x);
    return x;
}

// W row (16 floats) as 8 packed pairs over r
__device__ __forceinline__ void loadW(const float* __restrict__ p, v2f (&W)[8]) {
    const float4 w0 = *reinterpret_cast<const float4*>(p);
    const float4 w1 = *reinterpret_cast<const float4*>(p + 4);
    const float4 w2 = *reinterpret_cast<const float4*>(p + 8);
    const float4 w3 = *reinterpret_cast<const float4*>(p + 12);
    W[0].x=w0.x; W[0].y=w0.y; W[1].x=w0.z; W[1].y=w0.w;
    W[2].x=w1.x; W[2].y=w1.y; W[3].x=w1.z; W[3].y=w1.w;
    W[4].x=w2.x; W[4].y=w2.y; W[5].x=w2.z; W[5].y=w2.w;
    W[6].x=w3.x; W[6].y=w3.y; W[7].x=w3.z; W[7].y=w3.w;
}

// votes from register-cached P: v[p*2+h] holds pose dims (4p+2h, 4p+2h+1)
__device__ __forceinline__ void vote8r(const float4 (&P)[4], const v2f (&W)[8], v2f (&v)[8]) {
    #pragma unroll
    for (int p = 0; p < 4; ++p) {
        const float4 pv = P[p];
        #pragma unroll
        for (int h = 0; h < 2; ++h) {
            v2f acc = splat(pv.w) * W[6 + h];
            acc = vfma(splat(pv.z), W[4 + h], acc);
            acc = vfma(splat(pv.y), W[2 + h], acc);
            acc = vfma(splat(pv.x), W[0 + h], acc);
            v[p * 2 + h] = acc;
        }
    }
}

// ---------------------------------------------------------------------------
// Single fused kernel (R21 structure, best known = 106.8us) + register
// double-buffered P/A prefetch: the 4x ds_read_b128 + sA read for step s+1
// are ISSUED before step s's softmax chain and consumed next step, hiding the
// ~120cy LDS latency that R21 exposed per step (the per-step stall R22's
// wave-count experiment localized inside the step). W ping-pong unchanged.
// launch_bounds (256,1): VGPR cap 256 (need ~140; at 140 -> 3 waves/SIMD =
// 12 waves/CU >= the 9 needed for all 576 blocks resident).
// ---------------------------------------------------------------------------
__global__ __launch_bounds__(256, 1)
void caps_fused(const float* __restrict__ pose_in,   // [4,14,14,32,16]
                const float* __restrict__ act_in,    // [4,14,14,32]
                const float* __restrict__ wmat,      // [288,32,16]
                const float* __restrict__ beta_v,    // [32]
                const float* __restrict__ beta_a,    // [32]
                float* __restrict__ out)             // pose ++ act
{
    __shared__ __align__(16) float sP[NI * PD];      // 18.4 KB full patch
    __shared__ float sA[NI];
    __shared__ __align__(8) float sStat[OCAP][2 * PD + 2]; // [o][0..15]=i2, [16..31]=ng
    __shared__ float sBias[OCAP];
    __shared__ float sRed[2][33][33];                // 2-phase cross-wave partials

    const int n  = blockIdx.x;
    const int b  = n / (SOUT * SOUT);
    const int yx = n % (SOUT * SOUT);
    const int y  = yx / SOUT;
    const int x  = yx % SOUT;

    const int t    = threadIdx.x;
    const int wave = t >> 6;            // 0..3
    const int o    = t & 31;
    const int slot = t >> 5;            // 0..7
    const int half = slot & 1;

    // ---- stage the full 288-cap patch ONCE (coalesced float4) ----
    {
        const float4* src = reinterpret_cast<const float4*>(pose_in);
        float4* dst = reinterpret_cast<float4*>(sP);
        for (int u = t; u < NI * 4; u += 256) {      // 1152 float4
            const int i = u >> 2, comp = u & 3;
            const int k = i >> 5, c = i & 31;
            const int ki = k / 3, kj = k - ki * 3;
            const int cell = (b * 14 + y + ki) * 14 + (x + kj);
            dst[u] = src[(size_t)(cell * 32 + c) * 4 + comp];
        }
        for (int u = t; u < NI; u += 256) {
            const int k = u >> 5, c = u & 31;
            const int ki = k / 3, kj = k - ki * 3;
            const int cell = (b * 14 + y + ki) * 14 + (x + kj);
            sA[u] = act_in[(size_t)cell * 32 + c];
        }
    }
    __syncthreads();

    // lane W base: i = step*8 + slot, row (i*32+o)*16; step stride 4096 floats
    const float* wth = wmat + ((size_t)(slot * OCAP + o)) * PD;
    const float4* sP4 = reinterpret_cast<const float4*>(sP);

    #pragma unroll 1
    for (int sweep = 0; sweep < 3; ++sweep) {
        // per-sweep register cache of the per-o stats
        float bias_r = 0.f;
        v2f i2r[8], ngr[8];
        if (sweep > 0) {
            bias_r = sBias[o];
            #pragma unroll
            for (int h = 0; h < 8; ++h) {
                i2r[h] = *reinterpret_cast<const v2f*>(&sStat[o][2 * h]);
                ngr[h] = *reinterpret_cast<const v2f*>(&sStat[o][16 + 2 * h]);
            }
        }

        v2f s1[8], s2[8];
        float s0acc = 0.f;
        #pragma unroll
        for (int h = 0; h < 8; ++h) { s1[h] = splat(0.f); s2[h] = splat(0.f); }

        v2f WA[8], WB[8];
        float4 PA[4], PB[4];
        float aA, aB;
        loadW(wth, WA);
        PA[0] = sP4[slot * 4 + 0]; PA[1] = sP4[slot * 4 + 1];
        PA[2] = sP4[slot * 4 + 2]; PA[3] = sP4[slot * 4 + 3];
        aA = sA[slot];

#define STEP(st_, Wc, Wn, Pc, Pn, ac, an)                                  \
        {                                                                  \
            if ((st_) < 35) {                                              \
                loadW(wth + (size_t)((st_) + 1) * 4096, Wn);               \
                const int iln = ((st_) + 1) * 8 + slot;                    \
                Pn[0] = sP4[iln * 4 + 0]; Pn[1] = sP4[iln * 4 + 1];        \
                Pn[2] = sP4[iln * 4 + 2]; Pn[3] = sP4[iln * 4 + 3];        \
                an = sA[iln];                                              \
            }                                                              \
            v2f v[8];                                                      \
            vote8r(Pc, Wc, v);                                             \
            const float a_i = ac;                                          \
            float rrp;                                                     \
            if (sweep == 0) {                                              \
                rrp = a_i * (1.0f / 32.0f);                                \
            } else {                                                       \
                v2f ts2 = splat(0.f);                                      \
                _Pragma("unroll")                                          \
                for (int h = 0; h < 8; ++h) {                              \
                    const v2f tmp = vfma(v[h], i2r[h], ngr[h]);            \
                    ts2 = vfma(v[h], tmp, ts2);                            \
                }                                                          \
                /* shift-invariant softmax, no max-sub (validated R13) */  \
                const float zz = bias_r - (ts2.x + ts2.y);                 \
                const float e = __expf(zz);                                \
                const float es = redsum32(e);                              \
                rrp = __fdividef(e, es) * a_i;                             \
            }                                                              \
            s0acc += rrp;                                                  \
            const v2f rr2 = splat(rrp);                                    \
            _Pragma("unroll")                                              \
            for (int h = 0; h < 8; ++h) {                                  \
                const v2f rv = rr2 * v[h];                                 \
                s1[h] = s1[h] + rv;                                        \
                s2[h] = vfma(rv, v[h], s2[h]);                             \
            }                                                              \
        }

        #pragma unroll 1
        for (int kk = 0; kk < 18; ++kk) {
            STEP(2 * kk,     WA, WB, PA, PB, aA, aB);
            STEP(2 * kk + 1, WB, WA, PB, PA, aB, aA);
        }
#undef STEP

        // fold slot pairs (lane^32: different i, same o) within each wave
        #pragma unroll
        for (int h = 0; h < 8; ++h) {
            s1[h].x += __shfl_xor(s1[h].x, 32, 64);
            s1[h].y += __shfl_xor(s1[h].y, 32, 64);
            s2[h].x += __shfl_xor(s2[h].x, 32, 64);
            s2[h].y += __shfl_xor(s2[h].y, 32, 64);
        }
        s0acc += __shfl_xor(s0acc, 32, 64);

        // two-phase cross-wave reduction into sRed (validated R16)
        if (wave < 2 && half == 0) {
            #pragma unroll
            for (int h = 0; h < 8; ++h) {
                sRed[wave][2 * h][o]          = s1[h].x;
                sRed[wave][2 * h + 1][o]      = s1[h].y;
                sRed[wave][16 + 2 * h][o]     = s2[h].x;
                sRed[wave][16 + 2 * h + 1][o] = s2[h].y;
            }
            sRed[wave][32][o] = s0acc;
        }
        __syncthreads();
        if (wave >= 2 && half == 0) {
            #pragma unroll
            for (int h = 0; h < 8; ++h) {
                sRed[wave - 2][2 * h][o]          += s1[h].x;
                sRed[wave - 2][2 * h + 1][o]      += s1[h].y;
                sRed[wave - 2][16 + 2 * h][o]     += s2[h].x;
                sRed[wave - 2][16 + 2 * h + 1][o] += s2[h].y;
            }
            sRed[wave - 2][32][o] += s0acc;
        }
        __syncthreads();

        // ---- block-local stats (sweep<2) or final output (sweep==2) ----
        {
            const int oo = t >> 3, dp = t & 7, d0 = dp * 2;
            const float S0  = sRed[0][32][oo]      + sRed[1][32][oo];
            const float S1a = sRed[0][d0][oo]      + sRed[1][d0][oo];
            const float S1b = sRed[0][d0 + 1][oo]  + sRed[1][d0 + 1][oo];
            const float S2a = sRed[0][16 + d0][oo] + sRed[1][16 + d0][oo];
            const float S2b = sRed[0][17 + d0][oo] + sRed[1][17 + d0][oo];
            const float inv = 1.f / S0;
            const float m0 = S1a * inv, m1 = S1b * inv;
            const float v0 = fmaxf(fmaf(-m0, m0, S2a * inv), 0.f);
            const float v1 = fmaxf(fmaf(-m1, m1, S2b * inv), 0.f);
            float ll = __logf(sqrtf(v0) + EPSF) + __logf(sqrtf(v1) + EPSF);

            if (sweep < 2) {
                const float i20 = 0.5f / fmaxf(v0, 1e-30f);
                const float i21 = 0.5f / fmaxf(v1, 1e-30f);
                float c0 = m0 * m0 * i20 + m1 * m1 * i21;
                sStat[oo][d0]      = i20;
                sStat[oo][d0 + 1]  = i21;
                sStat[oo][16 + d0] = -2.f * m0 * i20;
                sStat[oo][17 + d0] = -2.f * m1 * i21;
                #pragma unroll
                for (int m = 1; m <= 4; m <<= 1) {
                    ll += __shfl_xor(ll, m, 8);
                    c0 += __shfl_xor(c0, m, 8);
                }
                if (dp == 0) {
                    const float cost = S0 * fmaf(16.f, beta_v[oo], ll);
                    const float invtemp = 1.0f + (float)sweep;   // 1, 2
                    const float oact = 1.f / (1.f + __expf(-invtemp * (beta_a[oo] - cost)));
                    sBias[oo] = __logf(oact + EPSF) - ll - c0;
                }
            } else {
                float2 pv; pv.x = m0; pv.y = m1;
                *reinterpret_cast<float2*>(out + (size_t)n * (OCAP * PD) + oo * PD + d0) = pv;
                #pragma unroll
                for (int m = 1; m <= 4; m <<= 1)
                    ll += __shfl_xor(ll, m, 8);
                if (dp == 0) {
                    const float cost = S0 * fmaf(16.f, beta_v[oo], ll);
                    const float oact = 1.f / (1.f + __expf(-3.0f * (beta_a[oo] - cost)));
                    out[POSE_OUT + (size_t)n * OCAP + oo] = oact;
                }
            }
        }
        __syncthreads();   // sStat/sBias visible; sRed safe to overwrite
    }
}

} // namespace

extern "C" void kernel_launch(void* const* d_in, const int* in_sizes, int n_in,
                              void* d_out, int out_size, void* d_ws, size_t ws_size,
                              hipStream_t stream) {
    const float* pose_in = (const float*)d_in[0];
    const float* act_in  = (const float*)d_in[1];
    const float* wmat    = (const float*)d_in[2];
    const float* beta_v  = (const float*)d_in[3];
    const float* beta_a  = (const float*)d_in[4];
    float* out = (float*)d_out;

    caps_fused<<<dim3(NPOS), dim3(256), 0, stream>>>(
        pose_in, act_in, wmat, beta_v, beta_a, out);
}